// Round 3
// baseline (453.005 us; speedup 1.0000x reference)
//
#include <hip/hip_runtime.h>
#include <math.h>

#define SEQ      8192
#define NTHREADS 256
#define WPB      4            // waves per block, one row per wave
#define VPT      128          // values per lane (64 lanes * 128 = 8192)
#define F4PT     32           // float4 loads per lane

__device__ __forceinline__ float wave_sum(float x) {
    #pragma unroll
    for (int off = 32; off > 0; off >>= 1)
        x += __shfl_xor(x, off, 64);
    return x;
}

// One wave per row: the whole row lives in this wave's registers, all 21
// reductions are intra-wave shuffles. No LDS, no __syncthreads, no
// block-wide barrier drains -- each wave runs its serial phase chain
// independently, so resident waves latency-hide each other.
__global__ __launch_bounds__(NTHREADS, 2) void normalizer_kernel(
        const float* __restrict__ score,
        const int*   __restrict__ mask,
        float*       __restrict__ out)
{
    const int tid  = threadIdx.x;
    const int wid  = tid >> 6;
    const int lane = tid & 63;
    const int row  = blockIdx.x * WPB + wid;

    constexpr double L2E = 1.4426950408889634;
    const float cf = (float)(L2E / 0.3);          // score -> w domain

    const float4* __restrict__ s4 = (const float4*)(score + (size_t)row * SEQ);
    const int4*   __restrict__ m4 = (const int4*)(mask  + (size_t)row * SEQ);

    // w = score * log2e/0.3 ; masked -> -inf (exp2(-inf)=0 handles all sums)
    float w[VPT];
    float cntf = 0.f;
    #pragma unroll
    for (int j = 0; j < F4PT; ++j) {
        float4 s = s4[j * 64 + lane];
        int4   m = m4[j * 64 + lane];
        w[4*j+0] = m.x ? s.x * cf : -INFINITY;
        w[4*j+1] = m.y ? s.y * cf : -INFINITY;
        w[4*j+2] = m.z ? s.z * cf : -INFINITY;
        w[4*j+3] = m.w ? s.w * cf : -INFINITY;
        cntf += (float)((m.x != 0) + (m.y != 0) + (m.z != 0) + (m.w != 0));
    }

    const float k    = 0.1f * wave_sum(cntf);
    const float l2k  = __builtin_amdgcn_logf(k);   // v_log_f32 = log2
    const float rk   = 1.0f / k;

    // b = -relu(score+a)  =>  score+b = min(score,-a); NA = -a in w-domain.
    float NA  = INFINITY;
    float cp  = 0.075f;        // 0.3/theta_t, theta_0 = 4.0
    float inv = 13.333333f;    // theta_t/0.3

    // t = 0..7: theta unclamped. Rolled outer loop (code stays < L1I).
    for (int t = 0; t < 8; ++t) {
        float a0 = 0.f, a1 = 0.f, a2 = 0.f, a3 = 0.f;
        #pragma unroll
        for (int j = 0; j < VPT; j += 4) {
            a0 += __builtin_amdgcn_exp2f(fminf(w[j+0], NA) * cp);
            a1 += __builtin_amdgcn_exp2f(fminf(w[j+1], NA) * cp);
            a2 += __builtin_amdgcn_exp2f(fminf(w[j+2], NA) * cp);
            a3 += __builtin_amdgcn_exp2f(fminf(w[j+3], NA) * cp);
        }
        const float s = wave_sum((a0 + a1) + (a2 + a3));
        NA = inv * (__builtin_amdgcn_logf(s + 1e-20f) - l2k);
        cp  *= 1.4285715f;     // 1/0.7
        inv *= 0.7f;
    }

    // Switch to e = exp2(w) (monotone: exp2(min(w,NA)) = min(e, eNA)).
    #pragma unroll
    for (int j = 0; j < VPT; ++j)
        w[j] = __builtin_amdgcn_exp2f(w[j]);
    float eNA = __builtin_amdgcn_exp2f(NA);

    // t = 8..19: theta = 0.3. s = sum(min(e,eNA)); eNA' = (s+eps)/k. No exps.
    for (int t = 8; t < 20; ++t) {
        float a0 = 0.f, a1 = 0.f, a2 = 0.f, a3 = 0.f;
        #pragma unroll
        for (int j = 0; j < VPT; j += 4) {
            a0 += fminf(w[j+0], eNA);
            a1 += fminf(w[j+1], eNA);
            a2 += fminf(w[j+2], eNA);
            a3 += fminf(w[j+3], eNA);
        }
        const float s = wave_sum((a0 + a1) + (a2 + a3));
        eNA = (s + 1e-20f) * rk;
    }

    // gamma = min(e, eNA)/eNA; masked lanes have e=0 -> 0.
    const float r = 1.0f / eNA;
    float4* __restrict__ o4 = (float4*)(out + (size_t)row * SEQ);
    #pragma unroll
    for (int j = 0; j < F4PT; ++j) {
        float4 g;
        g.x = fminf(w[4*j+0], eNA) * r;
        g.y = fminf(w[4*j+1], eNA) * r;
        g.z = fminf(w[4*j+2], eNA) * r;
        g.w = fminf(w[4*j+3], eNA) * r;
        o4[j * 64 + lane] = g;
    }
}

extern "C" void kernel_launch(void* const* d_in, const int* in_sizes, int n_in,
                              void* d_out, int out_size, void* d_ws, size_t ws_size,
                              hipStream_t stream) {
    const float* score = (const float*)d_in[0];
    const int*   mask  = (const int*)d_in[1];
    float*       out   = (float*)d_out;
    const int rows = in_sizes[0] / SEQ;          // 4096
    normalizer_kernel<<<rows / WPB, NTHREADS, 0, stream>>>(score, mask, out);
}